// Round 1
// baseline (192.873 us; speedup 1.0000x reference)
//
#include <hip/hip_runtime.h>
#include <cstdint>
#include <cstddef>

#define NB 64
#define NS 2048
#define NH 512
#define NA 512

#define BM 64
#define BK 32

typedef __attribute__((ext_vector_type(8))) short short8;
typedef __attribute__((ext_vector_type(4))) float f32x4;

__device__ inline short f2bf(float f) {
    union { float f; uint32_t u; } v; v.f = f;
    uint32_t u = v.u;
    uint32_t r = (u + 0x7fffu + ((u >> 16) & 1u)) >> 16;
    return (short)r;
}

// ---------------- kernel 1a: dec_p[b][a] = dec[b]·W_dec[a] + b_dec[a] + b_enc[a]
__global__ __launch_bounds__(256) void k_decp(const float* __restrict__ dec,
                                              const float* __restrict__ Wd,
                                              const float* __restrict__ bd,
                                              const float* __restrict__ be,
                                              float* __restrict__ dp) {
    int b = blockIdx.x;
    __shared__ float dl[NH];
    for (int i = threadIdx.x; i < NH; i += 256) dl[i] = dec[b * NH + i];
    __syncthreads();
    for (int a = threadIdx.x; a < NA; a += 256) {
        const float4* wr = (const float4*)(Wd + (size_t)a * NH);
        float acc = 0.f;
#pragma unroll 8
        for (int h4 = 0; h4 < NH / 4; ++h4) {
            float4 w = wr[h4];
            acc += dl[h4*4+0]*w.x + dl[h4*4+1]*w.y + dl[h4*4+2]*w.z + dl[h4*4+3]*w.w;
        }
        dp[b * NA + a] = acc + bd[a] + be[a];
    }
}

// ---------------- kernel 1b: pack W_enc fp32 -> bf16, K-tiled + slot-swizzled
// layout: ws_W[kt][a][slot^( (a>>1)&3 )][8 bf16], kt=0..15 (32-k tiles), slot=k/8 within tile
__global__ __launch_bounds__(256) void k_packw(const float* __restrict__ We,
                                               short* __restrict__ wsw) {
    int t = blockIdx.x * 256 + threadIdx.x;      // 0..32767
    int slot = t & 3;
    int a = (t >> 2) & (NA - 1);
    int kt = t >> 11;                             // 0..15
    const float* src = We + (size_t)a * NH + kt * 32 + slot * 8;
    int dslot = slot ^ ((a >> 1) & 3);
    short* dst = wsw + (((size_t)kt * NA + a) * 4 + dslot) * 8;
    short8 o;
#pragma unroll
    for (int j = 0; j < 8; ++j) o[j] = f2bf(src[j]);
    *(short8*)dst = o;
}

// ---------------- kernel 2: fused enc projection + tanh + dot(V) -> scores
// grid: (B*S)/BM blocks, 256 threads (4 waves). Wave w covers a in [w*128, w*128+128).
// Per K-step: W tile (512a x 32k bf16, 32KB) via global_load_lds from pre-packed ws_W;
// A tile (64s x 32k) reg-staged fp32->bf16 with matching slot swizzle.
__global__ __launch_bounds__(256, 2) void k_scores(const float* __restrict__ enc,
                                                   const short* __restrict__ wsw,
                                                   const float* __restrict__ dp,
                                                   const float* __restrict__ V,
                                                   float* __restrict__ scores) {
    __shared__ short Wl[NA * BK];      // 32 KB
    __shared__ short Al[BM * BK];      // 4 KB
    __shared__ float sbuf[4][BM];      // 1 KB

    const int tid = threadIdx.x;
    const int w = tid >> 6;            // wave 0..3
    const int l = tid & 63;
    const int lrow = l & 15;
    const int lg = l >> 4;
    const int row0 = blockIdx.x * BM;  // flat row in [0, B*S)
    const int b = row0 / NS;

    // A staging: thread -> (row sa, k-quarter qa)
    const int sa = tid >> 2;
    const int qa = tid & 3;
    const float* encp = enc + (size_t)(row0 + sa) * NH + qa * 8;
    short* awr = Al + ((size_t)sa * 4 + (qa ^ ((sa >> 1) & 3))) * 8;

    const char* wsrc = (const char*)wsw;

    f32x4 acc[4][8];
#pragma unroll
    for (int i = 0; i < 4; ++i)
#pragma unroll
        for (int j = 0; j < 8; ++j) acc[i][j] = (f32x4){0.f, 0.f, 0.f, 0.f};

    for (int kt = 0; kt < NH / BK; ++kt) {
        // stage W: 32KB linear copy, 4 waves x 8 rounds x 1KB
#pragma unroll
        for (int r = 0; r < 8; ++r) {
            int blk = r * 4 + w;
            __builtin_amdgcn_global_load_lds(
                (const __attribute__((address_space(1))) void*)(wsrc + ((size_t)kt * 32768 + ((size_t)blk * 64 + l) * 16)),
                (__attribute__((address_space(3))) void*)((char*)Wl + blk * 1024),
                16, 0, 0);
        }
        // stage A (fp32 -> bf16)
        float4 f0 = *(const float4*)(encp);
        float4 f1 = *(const float4*)(encp + 4);
        short8 ab;
        ab[0] = f2bf(f0.x); ab[1] = f2bf(f0.y); ab[2] = f2bf(f0.z); ab[3] = f2bf(f0.w);
        ab[4] = f2bf(f1.x); ab[5] = f2bf(f1.y); ab[6] = f2bf(f1.z); ab[7] = f2bf(f1.w);
        *(short8*)awr = ab;
        encp += BK;
        __syncthreads();

        short8 af[4], bfr[8];
#pragma unroll
        for (int fm = 0; fm < 4; ++fm) {
            int row = fm * 16 + lrow;
            af[fm] = *(const short8*)(Al + ((size_t)row * 4 + (lg ^ ((row >> 1) & 3))) * 8);
        }
#pragma unroll
        for (int fn = 0; fn < 8; ++fn) {
            int arow = w * 128 + fn * 16 + lrow;
            bfr[fn] = *(const short8*)(Wl + ((size_t)arow * 4 + (lg ^ ((arow >> 1) & 3))) * 8);
        }
#pragma unroll
        for (int fm = 0; fm < 4; ++fm)
#pragma unroll
            for (int fn = 0; fn < 8; ++fn)
                acc[fm][fn] = __builtin_amdgcn_mfma_f32_16x16x32_bf16(af[fm], bfr[fn], acc[fm][fn], 0, 0, 0);
        __syncthreads();
    }

    // epilogue: tanh(acc + dec_p) * V, reduce over a
    float dpl[8], vl[8];
#pragma unroll
    for (int fn = 0; fn < 8; ++fn) {
        int a = w * 128 + fn * 16 + lrow;
        dpl[fn] = dp[b * NA + a];
        vl[fn] = V[a];
    }
    float ps[4][4];
#pragma unroll
    for (int fm = 0; fm < 4; ++fm)
#pragma unroll
        for (int i = 0; i < 4; ++i) ps[fm][i] = 0.f;

#pragma unroll
    for (int fm = 0; fm < 4; ++fm)
#pragma unroll
        for (int fn = 0; fn < 8; ++fn)
#pragma unroll
            for (int i = 0; i < 4; ++i) {
                float x = acc[fm][fn][i] + dpl[fn];
                // tanh(x) = 1 - 2/(exp2(x*2/ln2)+1)
                float u = exp2f(x * 2.885390082f);
                float th = 1.f - 2.f * __builtin_amdgcn_rcpf(u + 1.f);
                ps[fm][i] += th * vl[fn];
            }

#pragma unroll
    for (int fm = 0; fm < 4; ++fm)
#pragma unroll
        for (int i = 0; i < 4; ++i) {
            float v = ps[fm][i];
            v += __shfl_xor(v, 1);
            v += __shfl_xor(v, 2);
            v += __shfl_xor(v, 4);
            v += __shfl_xor(v, 8);
            if (lrow == 0) sbuf[w][fm * 16 + lg * 4 + i] = v;
        }
    __syncthreads();
    if (tid < BM) {
        float s = sbuf[0][tid] + sbuf[1][tid] + sbuf[2][tid] + sbuf[3][tid];
        scores[row0 + tid] = s;   // b_v omitted: softmax shift-invariant
    }
}

// ---------------- kernel 3: softmax over S per batch row
__global__ __launch_bounds__(256) void k_softmax(const float* __restrict__ scores,
                                                 float* __restrict__ attn) {
    int b = blockIdx.x;
    int tid = threadIdx.x;
    int l = tid & 63;
    int w = tid >> 6;
    const float4* src = (const float4*)(scores + (size_t)b * NS);
    float4 v0 = src[tid];
    float4 v1 = src[tid + 256];
    __shared__ float redm[4];
    __shared__ float reds[4];
    float m = fmaxf(fmaxf(fmaxf(v0.x, v0.y), fmaxf(v0.z, v0.w)),
                    fmaxf(fmaxf(v1.x, v1.y), fmaxf(v1.z, v1.w)));
#pragma unroll
    for (int off = 1; off < 64; off <<= 1) m = fmaxf(m, __shfl_xor(m, off));
    if (l == 0) redm[w] = m;
    __syncthreads();
    m = fmaxf(fmaxf(redm[0], redm[1]), fmaxf(redm[2], redm[3]));
    const float c = 1.4426950408889634f;
    float e[8];
    e[0] = exp2f((v0.x - m) * c); e[1] = exp2f((v0.y - m) * c);
    e[2] = exp2f((v0.z - m) * c); e[3] = exp2f((v0.w - m) * c);
    e[4] = exp2f((v1.x - m) * c); e[5] = exp2f((v1.y - m) * c);
    e[6] = exp2f((v1.z - m) * c); e[7] = exp2f((v1.w - m) * c);
    float s = e[0] + e[1] + e[2] + e[3] + e[4] + e[5] + e[6] + e[7];
#pragma unroll
    for (int off = 1; off < 64; off <<= 1) s += __shfl_xor(s, off);
    if (l == 0) reds[w] = s;
    __syncthreads();
    s = reds[0] + reds[1] + reds[2] + reds[3];
    float inv = 1.f / s;
    float4 o0 = { e[0]*inv, e[1]*inv, e[2]*inv, e[3]*inv };
    float4 o1 = { e[4]*inv, e[5]*inv, e[6]*inv, e[7]*inv };
    float4* dst = (float4*)(attn + (size_t)b * NS);
    dst[tid] = o0;
    dst[tid + 256] = o1;
}

// ---------------- kernel 4: ctx[b][h] = sum_s attn[b][s]*enc[b][s][h]; out = [ctx | dec]
// grid: B*4 blocks (b, h-chunk of 128), 512 threads (4 s-quarters x 128 h)
__global__ __launch_bounds__(512) void k_ctx(const float* __restrict__ enc,
                                             const float* __restrict__ attn,
                                             const float* __restrict__ dec,
                                             float* __restrict__ out) {
    int b = blockIdx.x >> 2;
    int c = blockIdx.x & 3;
    int tid = threadIdx.x;
    __shared__ float al[NS];
    __shared__ float sb[512];
    ((float4*)al)[tid] = ((const float4*)(attn + (size_t)b * NS))[tid];
    __syncthreads();
    int h = c * 128 + (tid & 127);
    int sq = tid >> 7;  // 0..3
    const float* ep = enc + (size_t)b * NS * NH + (size_t)(sq * 512) * NH + h;
    float acc = 0.f;
#pragma unroll 8
    for (int s = 0; s < 512; ++s) {
        acc += al[sq * 512 + s] * ep[(size_t)s * NH];
    }
    sb[tid] = acc;
    __syncthreads();
    if (tid < 128) {
        float ctx = sb[tid] + sb[tid + 128] + sb[tid + 256] + sb[tid + 384];
        out[(size_t)b * 1024 + c * 128 + tid] = ctx;
        out[(size_t)b * 1024 + 512 + c * 128 + tid] = dec[(size_t)b * NH + c * 128 + tid];
    }
}

extern "C" void kernel_launch(void* const* d_in, const int* in_sizes, int n_in,
                              void* d_out, int out_size, void* d_ws, size_t ws_size,
                              hipStream_t stream) {
    (void)in_sizes; (void)n_in; (void)out_size; (void)ws_size;
    const float* dec = (const float*)d_in[0];
    const float* enc = (const float*)d_in[1];
    const float* Wd  = (const float*)d_in[2];
    const float* bd  = (const float*)d_in[3];
    const float* We  = (const float*)d_in[4];
    const float* be  = (const float*)d_in[5];
    const float* V   = (const float*)d_in[6];
    // d_in[7] (b_v) unused: softmax is shift-invariant
    float* out = (float*)d_out;

    char* ws = (char*)d_ws;
    short* wsw    = (short*)ws;                                  // 512 KB bf16 packed W
    float* dpb    = (float*)(ws + 524288);                       // 128 KB dec_p
    float* scores = (float*)(ws + 524288 + 131072);              // 512 KB
    float* attn   = (float*)(ws + 524288 + 131072 + 524288);     // 512 KB

    k_decp<<<dim3(NB), dim3(256), 0, stream>>>(dec, Wd, bd, be, dpb);
    k_packw<<<dim3(128), dim3(256), 0, stream>>>(We, wsw);
    k_scores<<<dim3((NB * NS) / BM), dim3(256), 0, stream>>>(enc, wsw, dpb, V, scores);
    k_softmax<<<dim3(NB), dim3(256), 0, stream>>>(scores, attn);
    k_ctx<<<dim3(NB * 4), dim3(512), 0, stream>>>(enc, attn, dec, out);
}